// Round 1
// baseline (192.053 us; speedup 1.0000x reference)
//
#include <hip/hip_runtime.h>

#define BSZ 4096
#define LSEQ 1024
#define NAPP 10

__global__ __launch_bounds__(256) void sp_kernel(
    const float* __restrict__ x_features,
    const float* __restrict__ features,
    const float* __restrict__ emb,
    const float* __restrict__ fW1, const float* __restrict__ fb1,
    const float* __restrict__ fW2, const float* __restrict__ fb2,
    const float* __restrict__ fW3, const float* __restrict__ fb3,
    const float* __restrict__ rW1, const float* __restrict__ rb1,
    const float* __restrict__ rW2, const float* __restrict__ rb2,
    const float* __restrict__ rW3, const float* __restrict__ rb3,
    float* __restrict__ out)
{
    // ---- LDS ----
    __shared__ float embn[20];        // renormalized embedding (10 apps x 2)
    __shared__ float w1p[4][52];      // fW1 rows, K padded 50->52 with 0
    __shared__ float fb1p[52];        // fb1 padded with 0
    __shared__ float w2p[52][28];     // fW2 [K=52][J=28], pads 0
    __shared__ float fb2p[28];        // fb2 padded with 0
    __shared__ float w3t[5][28];      // fW3 transposed [m][j], pads 0
    __shared__ float fb3s[5];
    __shared__ float rw1s[700];       // rW1 [14][50]
    __shared__ float rb1s[50];
    __shared__ float rw2s[1250];      // rW2 [50][25]
    __shared__ float rb2s[25];
    __shared__ float rw3s[25];        // rW3 [25][1]
    __shared__ float rb3s;
    __shared__ float red[4][10];      // per-wave partials: 5 sum + 5 max
    __shared__ float hhs[14];
    __shared__ float r1buf[50];

    const int t = threadIdx.x;
    const int b = blockIdx.x;

    // ---- stage weights into LDS (with zero padding) ----
    for (int i = t; i < 4 * 52; i += 256) {
        int r = i / 52, k = i - r * 52;
        w1p[r][k] = (k < 50) ? fW1[r * 50 + k] : 0.f;
    }
    for (int i = t; i < 52; i += 256) fb1p[i] = (i < 50) ? fb1[i] : 0.f;
    for (int i = t; i < 52 * 28; i += 256) {
        int k = i / 28, j = i - k * 28;
        w2p[k][j] = (k < 50 && j < 25) ? fW2[k * 25 + j] : 0.f;
    }
    for (int i = t; i < 28; i += 256) fb2p[i] = (i < 25) ? fb2[i] : 0.f;
    for (int i = t; i < 5 * 28; i += 256) {
        int m = i / 28, j = i - m * 28;
        w3t[m][j] = (j < 25) ? fW3[j * 5 + m] : 0.f;
    }
    if (t < 5) fb3s[t] = fb3[t];
    for (int i = t; i < 700; i += 256) rw1s[i] = rW1[i];
    if (t < 50) rb1s[t] = rb1[t];
    for (int i = t; i < 1250; i += 256) rw2s[i] = rW2[i];
    if (t < 25) rb2s[t] = rb2[t];
    if (t < 25) rw3s[t] = rW3[t];
    if (t == 0) rb3s = rb3[0];
    if (t < NAPP) {
        float a0 = emb[2 * t], a1 = emb[2 * t + 1];
        float n = sqrtf(a0 * a0 + a1 * a1);
        float s = fminf(1.f, 1.f / fmaxf(n, 1e-7f));
        embn[2 * t] = a0 * s;
        embn[2 * t + 1] = a1 * s;
    }
    __syncthreads();

    // ---- per-position inputs (4 positions per lane, coalesced) ----
    const float* f0 = features + (size_t)b * (3 * LSEQ);
    float e0[4], e1[4], l0v[4], l1v[4];
    #pragma unroll
    for (int p = 0; p < 4; ++p) {
        int l = t + p * 256;
        int app = (int)f0[l];
        e0[p] = embn[2 * app];
        e1[p] = embn[2 * app + 1];
        l0v[p] = f0[LSEQ + l];
        l1v[p] = f0[2 * LSEQ + l];
    }

    // ---- h2 accumulators, init to fb2 (pads 0) ----
    float h2[4][28];
    #pragma unroll
    for (int j = 0; j < 28; ++j) {
        float bj = fb2p[j];
        h2[0][j] = bj; h2[1][j] = bj; h2[2][j] = bj; h2[3][j] = bj;
    }

    // ---- fused layer1 -> layer2, k-outer so each weight read serves 4 positions ----
    #pragma unroll 1
    for (int kg = 0; kg < 13; ++kg) {
        float4 wa = *(const float4*)&w1p[0][kg * 4];
        float4 wb = *(const float4*)&w1p[1][kg * 4];
        float4 wc = *(const float4*)&w1p[2][kg * 4];
        float4 wd = *(const float4*)&w1p[3][kg * 4];
        float4 bb = *(const float4*)&fb1p[kg * 4];
        float h1[4][4];
        #pragma unroll
        for (int p = 0; p < 4; ++p) {
            h1[p][0] = fmaxf(bb.x + e0[p] * wa.x + e1[p] * wb.x + l0v[p] * wc.x + l1v[p] * wd.x, 0.f);
            h1[p][1] = fmaxf(bb.y + e0[p] * wa.y + e1[p] * wb.y + l0v[p] * wc.y + l1v[p] * wd.y, 0.f);
            h1[p][2] = fmaxf(bb.z + e0[p] * wa.z + e1[p] * wb.z + l0v[p] * wc.z + l1v[p] * wd.z, 0.f);
            h1[p][3] = fmaxf(bb.w + e0[p] * wa.w + e1[p] * wb.w + l0v[p] * wc.w + l1v[p] * wd.w, 0.f);
        }
        #pragma unroll
        for (int r = 0; r < 4; ++r) {
            const int k = 0; (void)k;
            #pragma unroll
            for (int jg = 0; jg < 7; ++jg) {
                float4 w = *(const float4*)&w2p[kg * 4 + r][jg * 4];
                #pragma unroll
                for (int p = 0; p < 4; ++p) {
                    h2[p][jg * 4 + 0] += h1[p][r] * w.x;
                    h2[p][jg * 4 + 1] += h1[p][r] * w.y;
                    h2[p][jg * 4 + 2] += h1[p][r] * w.z;
                    h2[p][jg * 4 + 3] += h1[p][r] * w.w;
                }
            }
        }
    }
    // relu on h2 (pads stay 0: relu(0)=0)
    #pragma unroll
    for (int j = 0; j < 28; ++j) {
        h2[0][j] = fmaxf(h2[0][j], 0.f);
        h2[1][j] = fmaxf(h2[1][j], 0.f);
        h2[2][j] = fmaxf(h2[2][j], 0.f);
        h2[3][j] = fmaxf(h2[3][j], 0.f);
    }

    // ---- layer3: 25 -> 5 ----
    float h3[4][5];
    #pragma unroll
    for (int m = 0; m < 5; ++m) {
        float bm = fb3s[m];
        h3[0][m] = bm; h3[1][m] = bm; h3[2][m] = bm; h3[3][m] = bm;
        #pragma unroll
        for (int jg = 0; jg < 7; ++jg) {
            float4 w = *(const float4*)&w3t[m][jg * 4];
            #pragma unroll
            for (int p = 0; p < 4; ++p) {
                h3[p][m] += h2[p][jg * 4 + 0] * w.x + h2[p][jg * 4 + 1] * w.y
                          + h2[p][jg * 4 + 2] * w.z + h2[p][jg * 4 + 3] * w.w;
            }
        }
    }

    // ---- per-thread reduce over 4 positions, then wave shuffle reduce ----
    float s5[5], m5[5];
    #pragma unroll
    for (int m = 0; m < 5; ++m) {
        s5[m] = (h3[0][m] + h3[1][m]) + (h3[2][m] + h3[3][m]);
        m5[m] = fmaxf(fmaxf(h3[0][m], h3[1][m]), fmaxf(h3[2][m], h3[3][m]));
    }
    #pragma unroll
    for (int off = 32; off > 0; off >>= 1) {
        #pragma unroll
        for (int m = 0; m < 5; ++m) {
            s5[m] += __shfl_down(s5[m], off);
            m5[m] = fmaxf(m5[m], __shfl_down(m5[m], off));
        }
    }
    const int lane = t & 63, wid = t >> 6;
    if (lane == 0) {
        #pragma unroll
        for (int m = 0; m < 5; ++m) { red[wid][m] = s5[m]; red[wid][5 + m] = m5[m]; }
    }
    __syncthreads();

    // ---- combine waves + build hh[14] ----
    if (t < 5) {
        hhs[t] = (red[0][t] + red[1][t]) + (red[2][t] + red[3][t]);
    } else if (t < 10) {
        hhs[t] = fmaxf(fmaxf(red[0][t], red[1][t]), fmaxf(red[2][t], red[3][t]));
    } else if (t == 10) {
        int xa = (int)x_features[b * 3];
        hhs[10] = embn[2 * xa];
        hhs[11] = embn[2 * xa + 1];
        hhs[12] = x_features[b * 3 + 1];
        hhs[13] = x_features[b * 3 + 2];
    }
    __syncthreads();

    // ---- head MLP: 14 -> 50 -> 25 -> 1 on wave 0 ----
    if (t < 50) {
        float acc = rb1s[t];
        #pragma unroll
        for (int i = 0; i < 14; ++i) acc += hhs[i] * rw1s[i * 50 + t];
        r1buf[t] = fmaxf(acc, 0.f);
    }
    __syncthreads();

    float oacc = 0.f;
    if (t < 25) {
        float acc = rb2s[t];
        #pragma unroll
        for (int k = 0; k < 50; ++k) acc += r1buf[k] * rw2s[k * 25 + t];
        oacc = fmaxf(acc, 0.f) * rw3s[t];
    }
    #pragma unroll
    for (int off = 32; off > 0; off >>= 1) oacc += __shfl_down(oacc, off);
    if (t == 0) out[b] = oacc + rb3s;
}

extern "C" void kernel_launch(void* const* d_in, const int* in_sizes, int n_in,
                              void* d_out, int out_size, void* d_ws, size_t ws_size,
                              hipStream_t stream) {
    const float* x_features = (const float*)d_in[0];
    const float* features   = (const float*)d_in[1];
    // d_in[2] = lengths (dead in the math)
    const float* emb = (const float*)d_in[3];
    const float* fW1 = (const float*)d_in[4];
    const float* fb1 = (const float*)d_in[5];
    const float* fW2 = (const float*)d_in[6];
    const float* fb2 = (const float*)d_in[7];
    const float* fW3 = (const float*)d_in[8];
    const float* fb3 = (const float*)d_in[9];
    const float* rW1 = (const float*)d_in[10];
    const float* rb1 = (const float*)d_in[11];
    const float* rW2 = (const float*)d_in[12];
    const float* rb2 = (const float*)d_in[13];
    const float* rW3 = (const float*)d_in[14];
    const float* rb3 = (const float*)d_in[15];
    float* out = (float*)d_out;

    sp_kernel<<<BSZ, 256, 0, stream>>>(x_features, features, emb,
                                       fW1, fb1, fW2, fb2, fW3, fb3,
                                       rW1, rb1, rW2, rb2, rW3, rb3, out);
}

// Round 2
// 177.324 us; speedup vs baseline: 1.0831x; 1.0831x over previous
//
#include <hip/hip_runtime.h>

#define BSZ 4096
#define LSEQ 1024
#define NAPP 10

__global__ __launch_bounds__(512) void sp_kernel(
    const float* __restrict__ x_features,
    const float* __restrict__ features,
    const float* __restrict__ emb,
    const float* __restrict__ fW1, const float* __restrict__ fb1,
    const float* __restrict__ fW2, const float* __restrict__ fb2,
    const float* __restrict__ fW3, const float* __restrict__ fb3,
    const float* __restrict__ rW1, const float* __restrict__ rb1,
    const float* __restrict__ rW2, const float* __restrict__ rb2,
    const float* __restrict__ rW3, const float* __restrict__ rb3,
    float* __restrict__ out)
{
    // ---- LDS: only divergent-access data + head weights + reductions ----
    __shared__ float embn[20];        // renormalized embedding (10 apps x 2)
    __shared__ float rw1s[700];       // rW1 [14][50]  (per-lane t index -> LDS)
    __shared__ float rb1s[50];
    __shared__ float rw2s[1250];      // rW2 [50][25]
    __shared__ float rb2s[25];
    __shared__ float rw3s[25];
    __shared__ float rb3s;
    __shared__ float red[8][10];      // per-wave partials: 5 sum + 5 max
    __shared__ float hhs[14];
    __shared__ float r1buf[50];

    const int t = threadIdx.x;
    const int b = blockIdx.x;

    // ---- stage head weights + embedding into LDS ----
    for (int i = t; i < 700; i += 512) rw1s[i] = rW1[i];
    if (t < 50) rb1s[t] = rb1[t];
    for (int i = t; i < 1250; i += 512) rw2s[i] = rW2[i];
    if (t < 25) rb2s[t] = rb2[t];
    if (t < 25) rw3s[t] = rW3[t];
    if (t == 0) rb3s = rb3[0];
    if (t < NAPP) {
        float a0 = emb[2 * t], a1 = emb[2 * t + 1];
        float n = sqrtf(a0 * a0 + a1 * a1);
        float s = fminf(1.f, 1.f / fmaxf(n, 1e-7f));
        embn[2 * t] = a0 * s;
        embn[2 * t + 1] = a1 * s;
    }
    __syncthreads();

    // ---- per-position inputs (2 positions per lane, coalesced) ----
    const float* f0 = features + (size_t)b * (3 * LSEQ);
    float e0[2], e1[2], l0v[2], l1v[2];
    #pragma unroll
    for (int p = 0; p < 2; ++p) {
        int l = t + p * 512;
        int app = (int)f0[l];
        e0[p] = embn[2 * app];
        e1[p] = embn[2 * app + 1];
        l0v[p] = f0[LSEQ + l];
        l1v[p] = f0[2 * LSEQ + l];
    }

    // ---- h2 accumulators, init to fb2 (scalar/uniform loads) ----
    float h2[2][25];
    #pragma unroll
    for (int j = 0; j < 25; ++j) {
        float bj = fb2[j];
        h2[0][j] = bj; h2[1][j] = bj;
    }

    // ---- fused layer1 -> layer2; weights via wave-uniform (scalar) loads ----
    #pragma unroll 1
    for (int kg = 0; kg < 12; ++kg) {
        float h1[2][4];
        #pragma unroll
        for (int r = 0; r < 4; ++r) {
            const int k = kg * 4 + r;
            float wa = fW1[k];            // fW1[0][k]
            float wb = fW1[50 + k];       // fW1[1][k]
            float wc = fW1[100 + k];      // fW1[2][k]
            float wd = fW1[150 + k];      // fW1[3][k]
            float bk = fb1[k];
            #pragma unroll
            for (int p = 0; p < 2; ++p)
                h1[p][r] = fmaxf(bk + e0[p] * wa + e1[p] * wb + l0v[p] * wc + l1v[p] * wd, 0.f);
        }
        #pragma unroll
        for (int r = 0; r < 4; ++r) {
            const int k = kg * 4 + r;
            #pragma unroll
            for (int j = 0; j < 25; ++j) {
                float w = fW2[k * 25 + j];
                h2[0][j] += h1[0][r] * w;
                h2[1][j] += h1[1][r] * w;
            }
        }
    }
    // tail k = 48, 49
    {
        float h1[2][2];
        #pragma unroll
        for (int r = 0; r < 2; ++r) {
            const int k = 48 + r;
            float wa = fW1[k], wb = fW1[50 + k], wc = fW1[100 + k], wd = fW1[150 + k];
            float bk = fb1[k];
            #pragma unroll
            for (int p = 0; p < 2; ++p)
                h1[p][r] = fmaxf(bk + e0[p] * wa + e1[p] * wb + l0v[p] * wc + l1v[p] * wd, 0.f);
        }
        #pragma unroll
        for (int r = 0; r < 2; ++r) {
            const int k = 48 + r;
            #pragma unroll
            for (int j = 0; j < 25; ++j) {
                float w = fW2[k * 25 + j];
                h2[0][j] += h1[0][r] * w;
                h2[1][j] += h1[1][r] * w;
            }
        }
    }

    // relu on h2
    #pragma unroll
    for (int j = 0; j < 25; ++j) {
        h2[0][j] = fmaxf(h2[0][j], 0.f);
        h2[1][j] = fmaxf(h2[1][j], 0.f);
    }

    // ---- layer3: 25 -> 5 (weights uniform/scalar) ----
    float h3[2][5];
    #pragma unroll
    for (int m = 0; m < 5; ++m) {
        float bm = fb3[m];
        h3[0][m] = bm; h3[1][m] = bm;
        #pragma unroll
        for (int j = 0; j < 25; ++j) {
            float w = fW3[j * 5 + m];
            h3[0][m] += h2[0][j] * w;
            h3[1][m] += h2[1][j] * w;
        }
    }

    // ---- per-thread reduce over 2 positions, then wave shuffle reduce ----
    float s5[5], m5[5];
    #pragma unroll
    for (int m = 0; m < 5; ++m) {
        s5[m] = h3[0][m] + h3[1][m];
        m5[m] = fmaxf(h3[0][m], h3[1][m]);
    }
    #pragma unroll
    for (int off = 32; off > 0; off >>= 1) {
        #pragma unroll
        for (int m = 0; m < 5; ++m) {
            s5[m] += __shfl_down(s5[m], off);
            m5[m] = fmaxf(m5[m], __shfl_down(m5[m], off));
        }
    }
    const int lane = t & 63, wid = t >> 6;
    if (lane == 0) {
        #pragma unroll
        for (int m = 0; m < 5; ++m) { red[wid][m] = s5[m]; red[wid][5 + m] = m5[m]; }
    }
    __syncthreads();

    // ---- combine 8 waves + build hh[14] ----
    if (t < 5) {
        float s = red[0][t];
        #pragma unroll
        for (int w = 1; w < 8; ++w) s += red[w][t];
        hhs[t] = s;
    } else if (t < 10) {
        float m = red[0][t];
        #pragma unroll
        for (int w = 1; w < 8; ++w) m = fmaxf(m, red[w][t]);
        hhs[t] = m;
    } else if (t == 10) {
        int xa = (int)x_features[b * 3];
        hhs[10] = embn[2 * xa];
        hhs[11] = embn[2 * xa + 1];
        hhs[12] = x_features[b * 3 + 1];
        hhs[13] = x_features[b * 3 + 2];
    }
    __syncthreads();

    // ---- head MLP: 14 -> 50 -> 25 -> 1 on wave 0 ----
    if (t < 50) {
        float acc = rb1s[t];
        #pragma unroll
        for (int i = 0; i < 14; ++i) acc += hhs[i] * rw1s[i * 50 + t];
        r1buf[t] = fmaxf(acc, 0.f);
    }
    __syncthreads();

    float oacc = 0.f;
    if (t < 25) {
        float acc = rb2s[t];
        #pragma unroll
        for (int k = 0; k < 50; ++k) acc += r1buf[k] * rw2s[k * 25 + t];
        oacc = fmaxf(acc, 0.f) * rw3s[t];
    }
    if (t < 64) {
        #pragma unroll
        for (int off = 32; off > 0; off >>= 1) oacc += __shfl_down(oacc, off);
        if (t == 0) out[b] = oacc + rb3s;
    }
}

extern "C" void kernel_launch(void* const* d_in, const int* in_sizes, int n_in,
                              void* d_out, int out_size, void* d_ws, size_t ws_size,
                              hipStream_t stream) {
    const float* x_features = (const float*)d_in[0];
    const float* features   = (const float*)d_in[1];
    // d_in[2] = lengths (dead in the math)
    const float* emb = (const float*)d_in[3];
    const float* fW1 = (const float*)d_in[4];
    const float* fb1 = (const float*)d_in[5];
    const float* fW2 = (const float*)d_in[6];
    const float* fb2 = (const float*)d_in[7];
    const float* fW3 = (const float*)d_in[8];
    const float* fb3 = (const float*)d_in[9];
    const float* rW1 = (const float*)d_in[10];
    const float* rb1 = (const float*)d_in[11];
    const float* rW2 = (const float*)d_in[12];
    const float* rb2 = (const float*)d_in[13];
    const float* rW3 = (const float*)d_in[14];
    const float* rb3 = (const float*)d_in[15];
    float* out = (float*)d_out;

    sp_kernel<<<BSZ, 512, 0, stream>>>(x_features, features, emb,
                                       fW1, fb1, fW2, fb2, fW3, fb3,
                                       rW1, rb1, rW2, rb2, rW3, rb3, out);
}

// Round 3
// 170.079 us; speedup vs baseline: 1.1292x; 1.0426x over previous
//
#include <hip/hip_runtime.h>
#include <stdint.h>

#define BSZ 4096
#define LSEQ 1024
#define NAPP 10

typedef short short8 __attribute__((ext_vector_type(8)));
typedef float f32x4 __attribute__((ext_vector_type(4)));

union S8 { int i[4]; short8 v; };

__device__ __forceinline__ uint32_t pk_bf16x2(float a, float b) {
    uint32_t r;
    asm("v_cvt_pk_bf16_f32 %0, %1, %2" : "=v"(r) : "v"(a), "v"(b));
    return r;
}
__device__ __forceinline__ float bfhi_f32(uint32_t hd) {
    return __uint_as_float(hd & 0xFFFF0000u);
}
// order-proof split of (a,b) -> hi dword (bf16 pair, low half = a), lo dword
__device__ __forceinline__ void split_pair(float a, float b, int& dh, int& dl) {
    uint32_t ha = pk_bf16x2(a, a), hb = pk_bf16x2(b, b);
    float la = a - bfhi_f32(ha), lb = b - bfhi_f32(hb);
    uint32_t lda = pk_bf16x2(la, la), ldb = pk_bf16x2(lb, lb);
    dh = (int)__builtin_amdgcn_perm(hb, ha, 0x07060302u);
    dl = (int)__builtin_amdgcn_perm(ldb, lda, 0x07060302u);
}
__device__ __forceinline__ void build_frag(const float* w, short8& fh, short8& fl) {
    S8 H, L;
    #pragma unroll
    for (int d = 0; d < 4; ++d) split_pair(w[2*d], w[2*d+1], H.i[d], L.i[d]);
    fh = H.v; fl = L.v;
}
__device__ __forceinline__ f32x4 MFMA(short8 a, short8 b, f32x4 c) {
    return __builtin_amdgcn_mfma_f32_16x16x32_bf16(a, b, c, 0, 0, 0);
}

__global__ __launch_bounds__(256, 2) void sp_kernel(
    const float* __restrict__ x_features,
    const float* __restrict__ features,
    const float* __restrict__ emb,
    const float* __restrict__ fW1, const float* __restrict__ fb1,
    const float* __restrict__ fW2, const float* __restrict__ fb2,
    const float* __restrict__ fW3, const float* __restrict__ fb3,
    const float* __restrict__ rW1, const float* __restrict__ rb1,
    const float* __restrict__ rW2, const float* __restrict__ rb2,
    const float* __restrict__ rW3, const float* __restrict__ rb3,
    float* __restrict__ out)
{
    __shared__ float embn[20];
    __shared__ float rw1s[700];
    __shared__ float rb1s[50];
    __shared__ float rw2s[1250];
    __shared__ float rb2s[25];
    __shared__ float rw3s[25];
    __shared__ float rb3s;
    __shared__ float redS[4][5], redM[4][5];
    __shared__ float hhs[14];
    __shared__ float r1buf[50];

    const int t = threadIdx.x;
    const int b = blockIdx.x;
    const int lane = t & 63;
    const int wid = t >> 6;
    const int L = lane & 15;      // position slot / frag row-col index
    const int g = lane >> 4;      // k-group

    // ---- stage head weights + renormalized embedding ----
    for (int i = t; i < 700; i += 256) rw1s[i] = rW1[i];
    if (t < 50) rb1s[t] = rb1[t];
    for (int i = t; i < 1250; i += 256) rw2s[i] = rW2[i];
    if (t < 25) rb2s[t] = rb2[t];
    if (t < 25) rw3s[t] = rW3[t];
    if (t == 0) rb3s = rb3[0];
    if (t < NAPP) {
        float a0 = emb[2 * t], a1 = emb[2 * t + 1];
        float n = sqrtf(a0 * a0 + a1 * a1);
        float s = fminf(1.f, 1.f / fmaxf(n, 1e-7f));
        embn[2 * t] = a0 * s;
        embn[2 * t + 1] = a1 * s;
    }
    __syncthreads();

    // ---- preload A-side fragments (W^T with row permutation sigma) ----
    // sigma1(mt, i) = 32*(mt>>1) + 8*(i>>2) + 4*(mt&1) + (i&3)
    short8 a1h[4], a1l[4];
    #pragma unroll
    for (int mt = 0; mt < 4; ++mt) {
        float w[8];
        int j1 = ((mt >> 1) << 5) + ((L >> 2) << 3) + ((mt & 1) << 2) + (L & 3);
        #pragma unroll
        for (int r = 0; r < 8; ++r) {
            int k = 8 * g + r;
            float wv = 0.f;
            if (k < 4)       wv = (j1 < 50) ? fW1[k * 50 + j1] : 0.f;
            else if (k == 4) wv = (j1 < 50) ? fb1[j1] : (j1 == 50 ? 1.f : 0.f);
            w[r] = wv;
        }
        build_frag(w, a1h[mt], a1l[mt]);
    }
    // sigma2(mt2, i) = 8*(i>>2) + 4*mt2 + (i&3)
    short8 a2h[2][2], a2l[2][2];  // [kt][mt2]
    #pragma unroll
    for (int kt = 0; kt < 2; ++kt) {
        #pragma unroll
        for (int mt2 = 0; mt2 < 2; ++mt2) {
            float w[8];
            int j2 = ((L >> 2) << 3) + (mt2 << 2) + (L & 3);
            #pragma unroll
            for (int r = 0; r < 8; ++r) {
                int j1 = kt * 32 + 8 * g + r;
                float wv = 0.f;
                if (j1 < 50)       wv = (j2 < 25) ? fW2[j1 * 25 + j2] : 0.f;
                else if (j1 == 50) wv = (j2 < 25) ? fb2[j2] : (j2 == 25 ? 1.f : 0.f);
                w[r] = wv;
            }
            build_frag(w, a2h[kt][mt2], a2l[kt][mt2]);
        }
    }
    short8 a3h, a3l;
    {
        float w[8];
        int m = L;
        #pragma unroll
        for (int r = 0; r < 8; ++r) {
            int j2 = 8 * g + r;
            float wv = 0.f;
            if (j2 < 25)       wv = (m < 5) ? fW3[j2 * 5 + m] : 0.f;
            else if (j2 == 25) wv = (m < 5) ? fb3[m] : 0.f;
            w[r] = wv;
        }
        build_frag(w, a3h, a3l);
    }

    const float* f0 = features + (size_t)b * (3 * LSEQ);
    const bool is_g0 = (g == 0);

    float rs[4] = {0.f, 0.f, 0.f, 0.f};
    float rm[4] = {-3.4e38f, -3.4e38f, -3.4e38f, -3.4e38f};

    // ---- main loop: 16 tiles of 16 positions per wave ----
    #pragma unroll 1
    for (int it = 0; it < 16; ++it) {
        const int pos0 = (wid * 16 + it) * 16;
        const int l = pos0 + L;

        // B1 = X^T fragment: k = {e0, e1, l0, l1, 1, 0, 0, 0} (g==0 lanes only)
        float fa = f0[l];
        float l0v = f0[LSEQ + l];
        float l1v = f0[2 * LSEQ + l];
        int app = (int)fa;
        float e0 = embn[2 * app], e1 = embn[2 * app + 1];
        int d0h, d0l, d1h, d1l;
        split_pair(e0, e1, d0h, d0l);
        split_pair(l0v, l1v, d1h, d1l);
        S8 BH, BL;
        BH.i[0] = is_g0 ? d0h : 0;
        BH.i[1] = is_g0 ? d1h : 0;
        BH.i[2] = is_g0 ? 0x00003F80 : 0;   // [0 | bf16(1.0)] -> k=4 ones column
        BH.i[3] = 0;
        BL.i[0] = is_g0 ? d0l : 0;
        BL.i[1] = is_g0 ? d1l : 0;
        BL.i[2] = 0;
        BL.i[3] = 0;
        short8 b1h = BH.v, b1l = BL.v;

        // GEMM1: h1^T = W1eff^T @ X^T   (4 m-tiles)
        f32x4 h1[4];
        #pragma unroll
        for (int mt = 0; mt < 4; ++mt) {
            f32x4 acc = {0.f, 0.f, 0.f, 0.f};
            acc = MFMA(a1h[mt], b1h, acc);
            acc = MFMA(a1h[mt], b1l, acc);
            acc = MFMA(a1l[mt], b1h, acc);
            h1[mt] = acc;
        }
        // relu
        #pragma unroll
        for (int mt = 0; mt < 4; ++mt) {
            h1[mt][0] = fmaxf(h1[mt][0], 0.f);
            h1[mt][1] = fmaxf(h1[mt][1], 0.f);
            h1[mt][2] = fmaxf(h1[mt][2], 0.f);
            h1[mt][3] = fmaxf(h1[mt][3], 0.f);
        }
        // B2 frags straight from registers (sigma1 makes k-order line up)
        S8 B2H0, B2L0, B2H1, B2L1;
        split_pair(h1[0][0], h1[0][1], B2H0.i[0], B2L0.i[0]);
        split_pair(h1[0][2], h1[0][3], B2H0.i[1], B2L0.i[1]);
        split_pair(h1[1][0], h1[1][1], B2H0.i[2], B2L0.i[2]);
        split_pair(h1[1][2], h1[1][3], B2H0.i[3], B2L0.i[3]);
        split_pair(h1[2][0], h1[2][1], B2H1.i[0], B2L1.i[0]);
        split_pair(h1[2][2], h1[2][3], B2H1.i[1], B2L1.i[1]);
        split_pair(h1[3][0], h1[3][1], B2H1.i[2], B2L1.i[2]);
        split_pair(h1[3][2], h1[3][3], B2H1.i[3], B2L1.i[3]);
        short8 b2h[2] = {B2H0.v, B2H1.v};
        short8 b2l[2] = {B2L0.v, B2L1.v};

        // GEMM2: h2^T = W2eff^T @ h1^T  (2 m-tiles x 2 k-tiles)
        f32x4 h2[2];
        #pragma unroll
        for (int mt2 = 0; mt2 < 2; ++mt2) {
            f32x4 acc = {0.f, 0.f, 0.f, 0.f};
            #pragma unroll
            for (int kt = 0; kt < 2; ++kt) {
                acc = MFMA(a2h[kt][mt2], b2h[kt], acc);
                acc = MFMA(a2h[kt][mt2], b2l[kt], acc);
                acc = MFMA(a2l[kt][mt2], b2h[kt], acc);
            }
            h2[mt2] = acc;
        }
        #pragma unroll
        for (int mt2 = 0; mt2 < 2; ++mt2) {
            h2[mt2][0] = fmaxf(h2[mt2][0], 0.f);
            h2[mt2][1] = fmaxf(h2[mt2][1], 0.f);
            h2[mt2][2] = fmaxf(h2[mt2][2], 0.f);
            h2[mt2][3] = fmaxf(h2[mt2][3], 0.f);
        }
        // B3 frag
        S8 B3H, B3L;
        split_pair(h2[0][0], h2[0][1], B3H.i[0], B3L.i[0]);
        split_pair(h2[0][2], h2[0][3], B3H.i[1], B3L.i[1]);
        split_pair(h2[1][0], h2[1][1], B3H.i[2], B3L.i[2]);
        split_pair(h2[1][2], h2[1][3], B3H.i[3], B3L.i[3]);

        // GEMM3: h3^T = W3eff^T @ h2^T  (bias included via ones column)
        f32x4 h3 = {0.f, 0.f, 0.f, 0.f};
        h3 = MFMA(a3h, B3H.v, h3);
        h3 = MFMA(a3h, B3L.v, h3);
        h3 = MFMA(a3l, B3H.v, h3);

        // accumulate sum/max over this tile's 16 positions (lane holds its pos)
        #pragma unroll
        for (int r = 0; r < 4; ++r) {
            rs[r] += h3[r];
            rm[r] = fmaxf(rm[r], h3[r]);
        }
    }

    // ---- reduce over the 16 position-lanes within each 16-lane group ----
    #pragma unroll
    for (int off = 1; off <= 8; off <<= 1) {
        #pragma unroll
        for (int r = 0; r < 4; ++r) {
            rs[r] += __shfl_xor(rs[r], off);
            rm[r] = fmaxf(rm[r], __shfl_xor(rm[r], off));
        }
    }
    if (L == 0) {
        #pragma unroll
        for (int r = 0; r < 4; ++r) {
            int m = 4 * g + r;
            if (m < 5) { redS[wid][m] = rs[r]; redM[wid][m] = rm[r]; }
        }
    }
    __syncthreads();

    // ---- combine 4 waves + build hh[14] ----
    if (t < 5) {
        hhs[t] = (redS[0][t] + redS[1][t]) + (redS[2][t] + redS[3][t]);
    } else if (t < 10) {
        int m = t - 5;
        hhs[t] = fmaxf(fmaxf(redM[0][m], redM[1][m]), fmaxf(redM[2][m], redM[3][m]));
    } else if (t == 10) {
        int xa = (int)x_features[b * 3];
        hhs[10] = embn[2 * xa];
        hhs[11] = embn[2 * xa + 1];
        hhs[12] = x_features[b * 3 + 1];
        hhs[13] = x_features[b * 3 + 2];
    }
    __syncthreads();

    // ---- head MLP: 14 -> 50 -> 25 -> 1 ----
    if (t < 50) {
        float acc = rb1s[t];
        #pragma unroll
        for (int i = 0; i < 14; ++i) acc += hhs[i] * rw1s[i * 50 + t];
        r1buf[t] = fmaxf(acc, 0.f);
    }
    __syncthreads();

    float oacc = 0.f;
    if (t < 25) {
        float acc = rb2s[t];
        #pragma unroll
        for (int k = 0; k < 50; ++k) acc += r1buf[k] * rw2s[k * 25 + t];
        oacc = fmaxf(acc, 0.f) * rw3s[t];
    }
    if (t < 64) {
        #pragma unroll
        for (int off = 32; off > 0; off >>= 1) oacc += __shfl_down(oacc, off);
        if (t == 0) out[b] = oacc + rb3s;
    }
}

extern "C" void kernel_launch(void* const* d_in, const int* in_sizes, int n_in,
                              void* d_out, int out_size, void* d_ws, size_t ws_size,
                              hipStream_t stream) {
    const float* x_features = (const float*)d_in[0];
    const float* features   = (const float*)d_in[1];
    // d_in[2] = lengths (dead in the math)
    const float* emb = (const float*)d_in[3];
    const float* fW1 = (const float*)d_in[4];
    const float* fb1 = (const float*)d_in[5];
    const float* fW2 = (const float*)d_in[6];
    const float* fb2 = (const float*)d_in[7];
    const float* fW3 = (const float*)d_in[8];
    const float* fb3 = (const float*)d_in[9];
    const float* rW1 = (const float*)d_in[10];
    const float* rb1 = (const float*)d_in[11];
    const float* rW2 = (const float*)d_in[12];
    const float* rb2 = (const float*)d_in[13];
    const float* rW3 = (const float*)d_in[14];
    const float* rb3 = (const float*)d_in[15];
    float* out = (float*)d_out;

    sp_kernel<<<BSZ, 256, 0, stream>>>(x_features, features, emb,
                                       fW1, fb1, fW2, fb2, fW3, fb3,
                                       rW1, rb1, rW2, rb2, rW3, rb3, out);
}

// Round 4
// 97.365 us; speedup vs baseline: 1.9725x; 1.7468x over previous
//
#include <hip/hip_runtime.h>
#include <stdint.h>

#define BSZ 4096
#define LSEQ 1024

typedef short short8 __attribute__((ext_vector_type(8)));
typedef float f32x4 __attribute__((ext_vector_type(4)));

union S8 { int i[4]; short8 v; int4 q; };

__device__ __forceinline__ uint32_t pk_bf16x2(float a, float b) {
    uint32_t r;
    asm("v_cvt_pk_bf16_f32 %0, %1, %2" : "=v"(r) : "v"(a), "v"(b));
    return r;
}
// (a,b) -> hi dword [bf16(b)|bf16(a)], lo dword [bf16(b-bh)|bf16(a-ah)]
// 6 VALU ops; numerically identical to the round-3 10-op version.
__device__ __forceinline__ void split_pair(float a, float b, int& dh, int& dl) {
    uint32_t h = pk_bf16x2(a, b);
    float ah = __uint_as_float(h << 16);
    float bh = __uint_as_float(h & 0xFFFF0000u);
    dh = (int)h;
    dl = (int)pk_bf16x2(a - ah, b - bh);
}
__device__ __forceinline__ float bf16hi(float a) {   // rne-bf16(a) as f32
    uint32_t h = pk_bf16x2(a, a);
    return __uint_as_float(h & 0xFFFF0000u);
}
__device__ __forceinline__ f32x4 MFMA(short8 a, short8 b, f32x4 c) {
    return __builtin_amdgcn_mfma_f32_16x16x32_bf16(a, b, c, 0, 0, 0);
}

// ws layout (int units):
//   [0, 14*64*4)  : int4 frags [f=0..13][lane=0..63]
//   WS_EMBH + app : pre-split embedding hi dword (e0,e1)
//   WS_EMBL + app : lo dword
//   WS_EMBR + i   : raw normalized embedding floats [10][2]
#define WS_EMBH 3584
#define WS_EMBL 3600
#define WS_EMBR 3616

__global__ void sp_prep(const float* __restrict__ emb,
                        const float* __restrict__ fW1, const float* __restrict__ fb1,
                        const float* __restrict__ fW2, const float* __restrict__ fb2,
                        const float* __restrict__ fW3, const float* __restrict__ fb3,
                        int* __restrict__ ws)
{
    const int lane = threadIdx.x;          // 64 threads, 1 wave
    const int L = lane & 15, g = lane >> 4;
    int4* wf = (int4*)ws;

    // ---- A1: single frag per mt, 3-term split packed along K ----
    // k slots 0-4: Ah  (pairs with B=hi);  8-12: Ah (pairs with B=lo);
    // 16-20: Al (pairs with B=hi); everything else 0.
    #pragma unroll
    for (int mt = 0; mt < 4; ++mt) {
        int j1 = ((mt >> 1) << 5) + ((L >> 2) << 3) + ((mt & 1) << 2) + (L & 3);
        float v[8];
        #pragma unroll
        for (int e = 0; e < 8; ++e) {
            float src = 0.f;
            if (e < 4)       src = (j1 < 50) ? fW1[e * 50 + j1] : 0.f;
            else if (e == 4) src = (j1 < 50) ? fb1[j1] : (j1 == 50 ? 1.f : 0.f);
            float hi = bf16hi(src);
            float lo = src - hi;
            v[e] = (g < 2) ? hi : (g == 2 ? lo : 0.f);
        }
        S8 F;
        #pragma unroll
        for (int d = 0; d < 4; ++d) F.i[d] = (int)pk_bf16x2(v[2*d], v[2*d+1]);
        wf[mt * 64 + lane] = F.q;
    }

    // ---- A2 hi/lo frags (sigma2 row permutation, unchanged from verified r3) ----
    #pragma unroll
    for (int kt = 0; kt < 2; ++kt) {
        #pragma unroll
        for (int mt2 = 0; mt2 < 2; ++mt2) {
            int j2 = ((L >> 2) << 3) + (mt2 << 2) + (L & 3);
            float w[8];
            #pragma unroll
            for (int r = 0; r < 8; ++r) {
                int j1v = kt * 32 + 8 * g + r;
                float wv = 0.f;
                if (j1v < 50)       wv = (j2 < 25) ? fW2[j1v * 25 + j2] : 0.f;
                else if (j1v == 50) wv = (j2 < 25) ? fb2[j2] : (j2 == 25 ? 1.f : 0.f);
                w[r] = wv;
            }
            S8 H, Lo;
            #pragma unroll
            for (int d = 0; d < 4; ++d) split_pair(w[2*d], w[2*d+1], H.i[d], Lo.i[d]);
            wf[(4 + kt * 2 + mt2) * 64 + lane] = H.q;
            wf[(8 + kt * 2 + mt2) * 64 + lane] = Lo.q;
        }
    }

    // ---- A3 hi/lo frags ----
    {
        int m = L;
        float w[8];
        #pragma unroll
        for (int r = 0; r < 8; ++r) {
            int j2v = 8 * g + r;
            float wv = 0.f;
            if (j2v < 25)       wv = (m < 5) ? fW3[j2v * 5 + m] : 0.f;
            else if (j2v == 25) wv = (m < 5) ? fb3[m] : 0.f;
            w[r] = wv;
        }
        S8 H, Lo;
        #pragma unroll
        for (int d = 0; d < 4; ++d) split_pair(w[2*d], w[2*d+1], H.i[d], Lo.i[d]);
        wf[12 * 64 + lane] = H.q;
        wf[13 * 64 + lane] = Lo.q;
    }

    // ---- renormalized embedding: raw floats + pre-split hi/lo dwords ----
    if (lane < 10) {
        float a0 = emb[2 * lane], a1 = emb[2 * lane + 1];
        float n = sqrtf(a0 * a0 + a1 * a1);
        float s = fminf(1.f, 1.f / fmaxf(n, 1e-7f));
        float e0 = a0 * s, e1 = a1 * s;
        int dh, dl;
        split_pair(e0, e1, dh, dl);
        ws[WS_EMBH + lane] = dh;
        ws[WS_EMBL + lane] = dl;
        ((float*)ws)[WS_EMBR + 2 * lane] = e0;
        ((float*)ws)[WS_EMBR + 2 * lane + 1] = e1;
    }
}

__global__ __launch_bounds__(256, 3) void sp_main(
    const float* __restrict__ x_features,
    const float* __restrict__ features,
    const int* __restrict__ ws,
    const float* __restrict__ rW1, const float* __restrict__ rb1,
    const float* __restrict__ rW2, const float* __restrict__ rb2,
    const float* __restrict__ rW3, const float* __restrict__ rb3,
    float* __restrict__ out)
{
    __shared__ int embh[16], embl[16];
    __shared__ float embr[20];
    __shared__ float redS[4][5], redM[4][5];
    __shared__ float hhs[14];
    __shared__ float r1buf[50];

    const int t = threadIdx.x;
    const int b = blockIdx.x;
    const int lane = t & 63;
    const int wid = t >> 6;
    const int L = lane & 15;
    const int g = lane >> 4;

    // ---- load prepacked A fragments (L2-broadcast, 14 x int4 per lane) ----
    const int4* wf = (const int4*)ws;
    S8 A1[4], A2H[4], A2L[4], A3H, A3L;
    #pragma unroll
    for (int f = 0; f < 4; ++f)  A1[f].q  = wf[f * 64 + lane];
    #pragma unroll
    for (int f = 0; f < 4; ++f)  A2H[f].q = wf[(4 + f) * 64 + lane];
    #pragma unroll
    for (int f = 0; f < 4; ++f)  A2L[f].q = wf[(8 + f) * 64 + lane];
    A3H.q = wf[12 * 64 + lane];
    A3L.q = wf[13 * 64 + lane];

    if (t < 16) { embh[t] = ws[WS_EMBH + t]; embl[t] = ws[WS_EMBL + t]; }
    if (t < 20) embr[t] = ((const float*)ws)[WS_EMBR + t];
    __syncthreads();

    const bool glo = (g == 1);      // group 1 carries the B-lo copy
    const float* f0 = features + (size_t)b * (3 * LSEQ);

    float rs[4] = {0.f, 0.f, 0.f, 0.f};
    float rm[4] = {-3.4e38f, -3.4e38f, -3.4e38f, -3.4e38f};

    #pragma unroll 2
    for (int it = 0; it < 16; ++it) {
        const int l = (wid * 16 + it) * 16 + L;

        float fa  = f0[l];
        float l0v = f0[LSEQ + l];
        float l1v = f0[2 * LSEQ + l];
        int app = (int)fa;
        int d0h = embh[app], d0l = embl[app];
        int d1h, d1l;
        split_pair(l0v, l1v, d1h, d1l);

        // B1: per-group hi/lo select (A masks the rest of K with zeros)
        S8 B1;
        B1.i[0] = glo ? d0l : d0h;
        B1.i[1] = glo ? d1l : d1h;
        B1.i[2] = glo ? 0 : 0x00003F80;      // ones column (bias propagation)
        B1.i[3] = 0;

        // GEMM1: 4 MFMAs total (3-term split packed along K)
        f32x4 h1[4];
        #pragma unroll
        for (int mt = 0; mt < 4; ++mt) {
            f32x4 z = {0.f, 0.f, 0.f, 0.f};
            h1[mt] = MFMA(A1[mt].v, B1.v, z);
        }
        #pragma unroll
        for (int mt = 0; mt < 4; ++mt) {
            h1[mt][0] = fmaxf(h1[mt][0], 0.f);
            h1[mt][1] = fmaxf(h1[mt][1], 0.f);
            h1[mt][2] = fmaxf(h1[mt][2], 0.f);
            h1[mt][3] = fmaxf(h1[mt][3], 0.f);
        }

        // B2 frags straight from registers (sigma1 alignment, verified r3)
        S8 B2H0, B2L0, B2H1, B2L1;
        split_pair(h1[0][0], h1[0][1], B2H0.i[0], B2L0.i[0]);
        split_pair(h1[0][2], h1[0][3], B2H0.i[1], B2L0.i[1]);
        split_pair(h1[1][0], h1[1][1], B2H0.i[2], B2L0.i[2]);
        split_pair(h1[1][2], h1[1][3], B2H0.i[3], B2L0.i[3]);
        split_pair(h1[2][0], h1[2][1], B2H1.i[0], B2L1.i[0]);
        split_pair(h1[2][2], h1[2][3], B2H1.i[1], B2L1.i[1]);
        split_pair(h1[3][0], h1[3][1], B2H1.i[2], B2L1.i[2]);
        split_pair(h1[3][2], h1[3][3], B2H1.i[3], B2L1.i[3]);

        // GEMM2: 12 MFMAs
        f32x4 h2[2];
        #pragma unroll
        for (int mt2 = 0; mt2 < 2; ++mt2) {
            f32x4 acc = {0.f, 0.f, 0.f, 0.f};
            acc = MFMA(A2H[0 * 2 + mt2].v, B2H0.v, acc);
            acc = MFMA(A2H[0 * 2 + mt2].v, B2L0.v, acc);
            acc = MFMA(A2L[0 * 2 + mt2].v, B2H0.v, acc);
            acc = MFMA(A2H[1 * 2 + mt2].v, B2H1.v, acc);
            acc = MFMA(A2H[1 * 2 + mt2].v, B2L1.v, acc);
            acc = MFMA(A2L[1 * 2 + mt2].v, B2H1.v, acc);
            h2[mt2] = acc;
        }
        #pragma unroll
        for (int mt2 = 0; mt2 < 2; ++mt2) {
            h2[mt2][0] = fmaxf(h2[mt2][0], 0.f);
            h2[mt2][1] = fmaxf(h2[mt2][1], 0.f);
            h2[mt2][2] = fmaxf(h2[mt2][2], 0.f);
            h2[mt2][3] = fmaxf(h2[mt2][3], 0.f);
        }

        // B3 frag
        S8 B3H, B3L;
        split_pair(h2[0][0], h2[0][1], B3H.i[0], B3L.i[0]);
        split_pair(h2[0][2], h2[0][3], B3H.i[1], B3L.i[1]);
        split_pair(h2[1][0], h2[1][1], B3H.i[2], B3L.i[2]);
        split_pair(h2[1][2], h2[1][3], B3H.i[3], B3L.i[3]);

        // GEMM3: 3 MFMAs
        f32x4 h3 = {0.f, 0.f, 0.f, 0.f};
        h3 = MFMA(A3H.v, B3H.v, h3);
        h3 = MFMA(A3H.v, B3L.v, h3);
        h3 = MFMA(A3L.v, B3H.v, h3);

        #pragma unroll
        for (int r = 0; r < 4; ++r) {
            rs[r] += h3[r];
            rm[r] = fmaxf(rm[r], h3[r]);
        }
    }

    // ---- reduce over the 16 position-lanes within each 16-lane group ----
    #pragma unroll
    for (int off = 1; off <= 8; off <<= 1) {
        #pragma unroll
        for (int r = 0; r < 4; ++r) {
            rs[r] += __shfl_xor(rs[r], off);
            rm[r] = fmaxf(rm[r], __shfl_xor(rm[r], off));
        }
    }
    if (L == 0) {
        #pragma unroll
        for (int r = 0; r < 4; ++r) {
            int m = 4 * g + r;
            if (m < 5) { redS[wid][m] = rs[r]; redM[wid][m] = rm[r]; }
        }
    }
    __syncthreads();

    // ---- combine 4 waves + build hh[14] ----
    if (t < 5) {
        hhs[t] = (redS[0][t] + redS[1][t]) + (redS[2][t] + redS[3][t]);
    } else if (t < 10) {
        int m = t - 5;
        hhs[t] = fmaxf(fmaxf(redM[0][m], redM[1][m]), fmaxf(redM[2][m], redM[3][m]));
    } else if (t == 10) {
        int xa = (int)x_features[b * 3];
        hhs[10] = embr[2 * xa];
        hhs[11] = embr[2 * xa + 1];
        hhs[12] = x_features[b * 3 + 1];
        hhs[13] = x_features[b * 3 + 2];
    }
    __syncthreads();

    // ---- head MLP: 14 -> 50 -> 25 -> 1 (weights direct from L2) ----
    if (t < 50) {
        float acc = rb1[t];
        #pragma unroll
        for (int i = 0; i < 14; ++i) acc += hhs[i] * rW1[i * 50 + t];
        r1buf[t] = fmaxf(acc, 0.f);
    }
    __syncthreads();

    float oacc = 0.f;
    if (t < 25) {
        float acc = rb2[t];
        #pragma unroll
        for (int k = 0; k < 50; ++k) acc += r1buf[k] * rW2[k * 25 + t];
        oacc = fmaxf(acc, 0.f) * rW3[t];
    }
    if (t < 64) {
        #pragma unroll
        for (int off = 32; off > 0; off >>= 1) oacc += __shfl_down(oacc, off);
        if (t == 0) out[b] = oacc + rb3[0];
    }
}

extern "C" void kernel_launch(void* const* d_in, const int* in_sizes, int n_in,
                              void* d_out, int out_size, void* d_ws, size_t ws_size,
                              hipStream_t stream) {
    const float* x_features = (const float*)d_in[0];
    const float* features   = (const float*)d_in[1];
    // d_in[2] = lengths (dead in the math)
    const float* emb = (const float*)d_in[3];
    const float* fW1 = (const float*)d_in[4];
    const float* fb1 = (const float*)d_in[5];
    const float* fW2 = (const float*)d_in[6];
    const float* fb2 = (const float*)d_in[7];
    const float* fW3 = (const float*)d_in[8];
    const float* fb3 = (const float*)d_in[9];
    const float* rW1 = (const float*)d_in[10];
    const float* rb1 = (const float*)d_in[11];
    const float* rW2 = (const float*)d_in[12];
    const float* rb2 = (const float*)d_in[13];
    const float* rW3 = (const float*)d_in[14];
    const float* rb3 = (const float*)d_in[15];
    float* out = (float*)d_out;
    int* ws = (int*)d_ws;

    sp_prep<<<1, 64, 0, stream>>>(emb, fW1, fb1, fW2, fb2, fW3, fb3, ws);
    sp_main<<<BSZ, 256, 0, stream>>>(x_features, features, ws,
                                     rW1, rb1, rW2, rb2, rW3, rb3, out);
}